// Round 18
// baseline (85.881 us; speedup 1.0000x reference)
//
#include <hip/hip_runtime.h>
#include <math.h>

#define B_ 8
#define N_ 4096
// (1/sqrt(7)) * log2(e): Q pre-scale so logits are in base-2 domain (exp2 softmax)
#define SCALE2_ 0.54528747f

typedef __bf16 bf16x8 __attribute__((ext_vector_type(8)));
typedef float f32x4 __attribute__((ext_vector_type(4)));
typedef float f32x16 __attribute__((ext_vector_type(16)));
typedef unsigned short ushortx8 __attribute__((ext_vector_type(8)));
typedef unsigned short ushort;
typedef unsigned int uint;
typedef uint uint2v __attribute__((ext_vector_type(2)));

static __device__ __forceinline__ ushort f2bf(float f) {
  union { float f; unsigned u; } v; v.f = f;
  unsigned r = v.u + 0x7FFFu + ((v.u >> 16) & 1u);  // RNE
  return (ushort)(r >> 16);
}
static __device__ __forceinline__ uint pk2(float a, float b) {
  union { __bf16 h[2]; uint u; } v;
  v.h[0] = (__bf16)a; v.h[1] = (__bf16)b;
  return v.u;
}

// ---------------------------------------------------------------------------
// Kernel 1: projections, 6-PASS (was 12): y = mat(3) x o-half(2), 32 outputs
// per thread in 4 fully-unrolled groups of 8 -- no runtime-indexed acc array
// (rule #20: indexed acc[16] under unroll-1 = scratch traffic), halved x
// re-reads (192MB vs 384MB). Layouts unchanged (R12/R13-proven):
//   Qb row-major [b][n][64] (pre-scaled bf16)
//   KF[b][kvblk][ks(4)][h(2)][r32(32)][8]
//   VF[b][kvblk][ks2(2)][h(2)][o(64)][8]
// ---------------------------------------------------------------------------
__global__ __launch_bounds__(256)
void proj_kernel(const float* __restrict__ x,
                 const float* __restrict__ Wq, const float* __restrict__ bq,
                 const float* __restrict__ Wk, const float* __restrict__ bk,
                 const float* __restrict__ Wv, const float* __restrict__ bv,
                 ushort* __restrict__ Qb, ushort* __restrict__ KF,
                 ushort* __restrict__ VF)
{
  __shared__ ushort sm[256][33];   // V transpose staging (o-half = 32 cols)

  const int tid = threadIdx.x;
  const int gp  = (blockIdx.x << 8) + tid;
  const int b   = gp >> 12;
  const int y   = blockIdx.y;                // 0..5
  const int mat = y >> 1;                    // 0=Q 1=K 2=V
  const int oh  = y & 1;                     // o-half
  const int o0  = oh << 5;
  const int n   = gp & 4095;

  const float* xb = x + ((size_t)b << 18) + n;
  float xr[64];
  #pragma unroll
  for (int c = 0; c < 64; ++c) xr[c] = xb[(size_t)c << 12];

  const float* W    = (mat == 0) ? Wq : (mat == 1) ? Wk : Wv;
  const float* bias = (mat == 0) ? bq : (mat == 1) ? bk : bv;
  const float scl   = (mat == 0) ? SCALE2_ : 1.0f;

  // K fragment base for this pixel (kvblk = n>>5, r32 = n&31)
  const size_t kfA0 = ((size_t)(b * 128 + (n >> 5))) * 2048 + ((n & 31) << 3);
  const size_t qbase = ((size_t)gp << 6) + o0;

  #pragma unroll 1
  for (int g = 0; g < 4; ++g) {              // group of 8 outputs
    __align__(16) ushort hv[8];
    #pragma unroll
    for (int jj = 0; jj < 8; ++jj) {
      const int o = o0 + (g << 3) + jj;
      const float4* wr = (const float4*)(W + (o << 6));
      float a = bias[o];
      #pragma unroll
      for (int c4 = 0; c4 < 16; ++c4) {
        float4 w4 = wr[c4];
        a += w4.x * xr[4*c4] + w4.y * xr[4*c4+1] + w4.z * xr[4*c4+2] + w4.w * xr[4*c4+3];
      }
      a *= scl;
      if (mat == 2) sm[tid][(g << 3) + jj] = f2bf(a);
      else          hv[jj] = f2bf(a);
    }
    if (mat == 0) {
      *(ushortx8*)(Qb + qbase + (g << 3)) = *(const ushortx8*)&hv[0];
    } else if (mat == 1) {
      // o = o0 + g*8 + jj: ks = o>>4 = 2*oh + (g>>1), h = (o>>3)&1 = g&1
      const int ks = (oh << 1) + (g >> 1);
      const int hh = g & 1;
      *(ushortx8*)(KF + kfA0 + (ks << 9) + (hh << 8)) = *(const ushortx8*)&hv[0];
    }
  }

  if (mat == 2) {
    __syncthreads();
    // thread -> (kvbl = tid>>5 local kv-block, ol = tid&31 local o)
    const int ol   = tid & 31;
    const int kvbl = tid >> 5;                      // 0..7
    const int nb   = (blockIdx.x << 8) & 4095;
    const int kvblk = (nb >> 5) + kvbl;
    #pragma unroll
    for (int ks2 = 0; ks2 < 2; ++ks2) {
      #pragma unroll
      for (int hh = 0; hh < 2; ++hh) {
        const int p0 = (kvbl << 5) + (ks2 << 4) + (hh << 3);   // pixel base
        uint pk[4];
        #pragma unroll
        for (int j = 0; j < 8; ++j) {
          ushort v = sm[p0 + j][ol];
          if (j & 1) pk[j >> 1] |= (uint)v << 16; else pk[j >> 1] = v;
        }
        const size_t A = ((size_t)(b * 128 + kvblk)) * 2048 + (ks2 << 10)
                       + (hh << 9) + ((o0 + ol) << 3);
        *(ushortx8*)(VF + A) = *(ushortx8*)&pk[0];
      }
    }
  }
}

// ---------------------------------------------------------------------------
// Kernel 2: flash attention (R17, unchanged -- best measured 64.0us).
// Fragment-direct from L2, 1024 blocks = (b, 32q) x 4 waves = 4 kv-quarters,
// zero main-loop barriers; sched_barrier-fenced depth-1 prefetch.
// ---------------------------------------------------------------------------
__global__ __launch_bounds__(256, 2)
void flash_kernel(const ushort* __restrict__ Qb, const ushort* __restrict__ KF,
                  const ushort* __restrict__ VF, float* __restrict__ out)
{
  __shared__ float cmb[3][64][33];   // 25.3 KB, end merge only

  const int tid  = threadIdx.x;
  const int lane = tid & 63;
  const int w    = tid >> 6;       // kv-quarter 0..3
  const int r32  = lane & 31;
  const int h    = lane >> 5;      // 0..1
  const int h8   = h << 3;

  const int bidx = (blockIdx.x & 7) * 128 + (blockIdx.x >> 3);
  const int b  = bidx >> 7;
  const int qw = (bidx & 127) << 5;           // block's 32-q window

  bf16x8 qf[4];
  {
    const ushort* qp = Qb + ((((size_t)b << 12) + qw + r32) << 6) + h8;
    #pragma unroll
    for (int ks = 0; ks < 4; ++ks) qf[ks] = *(const bf16x8*)(qp + (ks << 4));
  }

  const ushort* kb = KF + ((size_t)((b << 7) + (w << 5))) * 2048 + (lane << 3);
  const ushort* vb = VF + ((size_t)((b << 7) + (w << 5))) * 2048 + (h << 9) + (r32 << 3);

  const f32x16 Z = (f32x16)(0.0f);
  f32x16 acc0 = Z, acc1 = Z;
  float l_lane = 0.f;

  bf16x8 kA[4], vA[4], kB[4], vB[4];
  #define LDK(D, P) do { \
    D[0] = *(const bf16x8*)(P); \
    D[1] = *(const bf16x8*)((P) + 512); \
    D[2] = *(const bf16x8*)((P) + 1024); \
    D[3] = *(const bf16x8*)((P) + 1536); \
  } while (0)
  #define LDV(D, P) do { \
    D[0] = *(const bf16x8*)(P); \
    D[1] = *(const bf16x8*)((P) + 256); \
    D[2] = *(const bf16x8*)((P) + 1024); \
    D[3] = *(const bf16x8*)((P) + 1280); \
  } while (0)

  #define COMPUTE(KFr, VFr) do { \
    __builtin_amdgcn_s_setprio(1); \
    f32x16 s = __builtin_amdgcn_mfma_f32_32x32x16_bf16(KFr[0], qf[0], Z, 0, 0, 0); \
    s = __builtin_amdgcn_mfma_f32_32x32x16_bf16(KFr[1], qf[1], s, 0, 0, 0); \
    s = __builtin_amdgcn_mfma_f32_32x32x16_bf16(KFr[2], qf[2], s, 0, 0, 0); \
    s = __builtin_amdgcn_mfma_f32_32x32x16_bf16(KFr[3], qf[3], s, 0, 0, 0); \
    __builtin_amdgcn_s_setprio(0); \
    float rs = 0.f; \
    _Pragma("unroll") \
    for (int ii = 0; ii < 16; ++ii) { \
      float p = __builtin_exp2f(s[ii]); \
      s[ii] = p; \
      rs += p; \
    } \
    l_lane += rs; \
    bf16x8 pb0, pb1; \
    { \
      uint plo0 = pk2(s[0], s[1]); \
      uint plo1 = pk2(s[2], s[3]); \
      uint phi0 = pk2(s[4], s[5]); \
      uint phi1 = pk2(s[6], s[7]); \
      uint2v r0 = __builtin_amdgcn_permlane32_swap(plo0, phi0, false, false); \
      uint2v r1 = __builtin_amdgcn_permlane32_swap(plo1, phi1, false, false); \
      union { uint u[4]; bf16x8 v; } f_; \
      f_.u[0] = r0.x; f_.u[1] = r1.x; f_.u[2] = r0.y; f_.u[3] = r1.y; \
      pb0 = f_.v; \
    } \
    { \
      uint plo0 = pk2(s[8],  s[9]); \
      uint plo1 = pk2(s[10], s[11]); \
      uint phi0 = pk2(s[12], s[13]); \
      uint phi1 = pk2(s[14], s[15]); \
      uint2v r0 = __builtin_amdgcn_permlane32_swap(plo0, phi0, false, false); \
      uint2v r1 = __builtin_amdgcn_permlane32_swap(plo1, phi1, false, false); \
      union { uint u[4]; bf16x8 v; } f_; \
      f_.u[0] = r0.x; f_.u[1] = r1.x; f_.u[2] = r0.y; f_.u[3] = r1.y; \
      pb1 = f_.v; \
    } \
    __builtin_amdgcn_s_setprio(1); \
    acc0 = __builtin_amdgcn_mfma_f32_32x32x16_bf16(VFr[0], pb0, acc0, 0, 0, 0); \
    acc1 = __builtin_amdgcn_mfma_f32_32x32x16_bf16(VFr[1], pb0, acc1, 0, 0, 0); \
    acc0 = __builtin_amdgcn_mfma_f32_32x32x16_bf16(VFr[2], pb1, acc0, 0, 0, 0); \
    acc1 = __builtin_amdgcn_mfma_f32_32x32x16_bf16(VFr[3], pb1, acc1, 0, 0, 0); \
    __builtin_amdgcn_s_setprio(0); \
  } while (0)

  LDK(kA, kb); LDV(vA, vb);
  #pragma unroll 1
  for (int t = 0; t < 16; ++t) {
    kb += 2048; vb += 2048;
    LDK(kB, kb); LDV(vB, vb);
    __builtin_amdgcn_sched_barrier(0);
    COMPUTE(kA, vA);
    kb += 2048; vb += 2048;
    LDK(kA, kb); LDV(vA, vb);
    __builtin_amdgcn_sched_barrier(0);
    COMPUTE(kB, vB);
  }

  float l_me = l_lane + __shfl_xor(l_lane, 32);

  if (w != 0) {
    float* p = &cmb[w - 1][lane][0];
    #pragma unroll
    for (int i = 0; i < 16; ++i) { p[i] = acc0[i]; p[16 + i] = acc1[i]; }
    p[32] = l_me;
  }
  __syncthreads();
  if (w == 0) {
    float lsum = l_me;
    #pragma unroll
    for (int q = 0; q < 3; ++q) lsum += cmb[q][lane][32];
    const float inv = 1.0f / lsum;
    const size_t rowb = (((size_t)b << 12) + qw + r32) << 6;
    #pragma unroll
    for (int g = 0; g < 4; ++g) {
      f32x4 o4;
      #pragma unroll
      for (int i = 0; i < 4; ++i) {
        float v = acc0[4*g + i];
        #pragma unroll
        for (int q = 0; q < 3; ++q) v += cmb[q][lane][4*g + i];
        o4[i] = v * inv;
      }
      *(f32x4*)(out + rowb + (g << 3) + (h << 2)) = o4;
    }
    #pragma unroll
    for (int g = 0; g < 4; ++g) {
      f32x4 o4;
      #pragma unroll
      for (int i = 0; i < 4; ++i) {
        float v = acc1[4*g + i];
        #pragma unroll
        for (int q = 0; q < 3; ++q) v += cmb[q][lane][16 + 4*g + i];
        o4[i] = v * inv;
      }
      *(f32x4*)(out + rowb + 32 + (g << 3) + (h << 2)) = o4;
    }
  }
  #undef LDK
  #undef LDV
  #undef COMPUTE
}

extern "C" void kernel_launch(void* const* d_in, const int* in_sizes, int n_in,
                              void* d_out, int out_size, void* d_ws, size_t ws_size,
                              hipStream_t stream) {
  (void)in_sizes; (void)n_in; (void)out_size; (void)ws_size;
  const float* x  = (const float*)d_in[0];
  const float* Wq = (const float*)d_in[1];
  const float* bq = (const float*)d_in[2];
  const float* Wk = (const float*)d_in[3];
  const float* bk = (const float*)d_in[4];
  const float* Wv = (const float*)d_in[5];
  const float* bv = (const float*)d_in[6];
  float* out = (float*)d_out;

  const size_t SZ = (size_t)B_ * N_ * 64;          // 2,097,152 elems (4 MB)
  ushort* Qb = (ushort*)d_ws;
  ushort* KF = Qb + SZ;
  ushort* VF = KF + SZ;                            // + slack for 1-blk overrun

  proj_kernel<<<dim3(128, 6), dim3(256), 0, stream>>>(x, Wq, bq, Wk, bk, Wv, bv,
                                                      Qb, KF, VF);
  flash_kernel<<<dim3(1024), dim3(256), 0, stream>>>(Qb, KF, VF, out);
}

// Round 19
// 80.521 us; speedup vs baseline: 1.0666x; 1.0666x over previous
//
#include <hip/hip_runtime.h>
#include <math.h>

#define B_ 8
#define N_ 4096
// (1/sqrt(7)) * log2(e): Q pre-scale so logits are in base-2 domain (exp2 softmax)
#define SCALE2_ 0.54528747f

typedef __bf16 bf16x8 __attribute__((ext_vector_type(8)));
typedef float f32x4 __attribute__((ext_vector_type(4)));
typedef float f32x16 __attribute__((ext_vector_type(16)));
typedef unsigned short ushortx8 __attribute__((ext_vector_type(8)));
typedef unsigned short ushort;
typedef unsigned int uint;
typedef uint uint2v __attribute__((ext_vector_type(2)));

static __device__ __forceinline__ ushort f2bf(float f) {
  union { float f; unsigned u; } v; v.f = f;
  unsigned r = v.u + 0x7FFFu + ((v.u >> 16) & 1u);  // RNE
  return (ushort)(r >> 16);
}
static __device__ __forceinline__ uint pk2(float a, float b) {
  union { __bf16 h[2]; uint u; } v;
  v.h[0] = (__bf16)a; v.h[1] = (__bf16)b;
  return v.u;
}

// ---------------------------------------------------------------------------
// Kernel 1: projections, 12-pass (measured-best form). Qb row-major [b][n][64]
// (pre-scaled bf16); K/V in MFMA-FRAGMENT-MAJOR layouts:
//   KF[b][kvblk][ks(4)][h(2)][r32(32)][8]
//   VF[b][kvblk][ks2(2)][h(2)][o(64)][8]
// ---------------------------------------------------------------------------
__global__ __launch_bounds__(256)
void proj_kernel(const float* __restrict__ x,
                 const float* __restrict__ Wq, const float* __restrict__ bq,
                 const float* __restrict__ Wk, const float* __restrict__ bk,
                 const float* __restrict__ Wv, const float* __restrict__ bv,
                 ushort* __restrict__ Qb, ushort* __restrict__ KF,
                 ushort* __restrict__ VF)
{
  __shared__ ushort sm[256][17];

  const int tid = threadIdx.x;
  const int gp  = (blockIdx.x << 8) + tid;
  const int b   = gp >> 12;
  const int y   = blockIdx.y;                // 0..11
  const int mat = y >> 2;                    // 0=Q 1=K 2=V
  const int o0  = (y & 3) << 4;
  const int n   = gp & 4095;

  const float* xb = x + ((size_t)b << 18) + n;
  float xr[64];
  #pragma unroll
  for (int c = 0; c < 64; ++c) xr[c] = xb[(size_t)c << 12];

  const float* W    = (mat == 0) ? Wq : (mat == 1) ? Wk : Wv;
  const float* bias = (mat == 0) ? bq : (mat == 1) ? bk : bv;

  float acc[16];
  #pragma unroll 1
  for (int j = 0; j < 16; ++j) {
    const float4* wr = (const float4*)(W + ((o0 + j) << 6));
    float a = bias[o0 + j];
    #pragma unroll
    for (int c4 = 0; c4 < 16; ++c4) {
      float4 w4 = wr[c4];
      a += w4.x * xr[4*c4] + w4.y * xr[4*c4+1] + w4.z * xr[4*c4+2] + w4.w * xr[4*c4+3];
    }
    acc[j] = a;
  }

  if (mat == 2) {
    // V -> VF fragment layout via LDS transpose
    #pragma unroll
    for (int j = 0; j < 16; ++j) sm[tid][j] = f2bf(acc[j]);
    __syncthreads();
    const int ol   = tid & 15;
    const int hh   = (tid >> 4) & 1;
    const int kvbl = tid >> 5;                      // 0..7 local kvblk
    const int nb   = (blockIdx.x << 8) & 4095;
    const int kvblk = (nb >> 5) + kvbl;
    #pragma unroll
    for (int ks2 = 0; ks2 < 2; ++ks2) {
      const int kvl = (kvbl << 5) + (ks2 << 4) + (hh << 3);
      uint pk[4];
      #pragma unroll
      for (int cj = 0; cj < 8; ++cj) {
        ushort v = sm[kvl + cj][ol];
        if (cj & 1) pk[cj >> 1] |= (uint)v << 16; else pk[cj >> 1] = v;
      }
      const size_t A = ((size_t)(b * 128 + kvblk)) * 2048 + (ks2 << 10)
                     + (hh << 9) + ((o0 + ol) << 3);
      *(ushortx8*)(VF + A) = *(ushortx8*)&pk[0];
    }
  } else if (mat == 1) {
    // K -> KF fragment layout (direct; 2 dense 16B chunks/thread)
    const int ks = y & 3;                            // = o0>>4
    __align__(16) ushort hv[16];
    #pragma unroll
    for (int j = 0; j < 16; ++j) hv[j] = f2bf(acc[j]);
    const size_t A0 = ((size_t)(b * 128 + (n >> 5))) * 2048 + (ks << 9)
                    + ((n & 31) << 3);
    *(ushortx8*)(KF + A0)       = *(const ushortx8*)&hv[0];   // h=0
    *(ushortx8*)(KF + A0 + 256) = *(const ushortx8*)&hv[8];   // h=1
  } else {
    __align__(16) ushort hv[16];
    #pragma unroll
    for (int j = 0; j < 16; ++j) hv[j] = f2bf(acc[j] * SCALE2_);
    const size_t base = ((size_t)gp << 6) + o0;
    *(ushortx8*)(Qb + base)     = *(const ushortx8*)&hv[0];
    *(ushortx8*)(Qb + base + 8) = *(const ushortx8*)&hv[8];
  }
}

// ---------------------------------------------------------------------------
// Kernel 2: flash attention, fragment-direct from L2 + 64q-per-wave K/V
// reuse (measured-best flash config, 64.3us). 512 blocks = (b, 64q) x 4
// waves (kv-quarters); zero main-loop barriers; each wave computes TWO 32-q
// tiles per loaded K/V fragment set. Max-free exp2 softmax (implicit m=0),
// permlane32_swap EXCH, 4-way LDS merge epilogue. No combine kernel.
// ---------------------------------------------------------------------------
__global__ __launch_bounds__(256, 2)
void flash_kernel(const ushort* __restrict__ Qb, const ushort* __restrict__ KF,
                  const ushort* __restrict__ VF, float* __restrict__ out)
{
  __shared__ float cmb[3][64][66];   // 50688 B, end merge only

  const int tid  = threadIdx.x;
  const int lane = tid & 63;
  const int w    = tid >> 6;       // kv-quarter 0..3
  const int r32  = lane & 31;
  const int h    = lane >> 5;      // 0..1
  const int h8   = h << 3;

  // 512 blocks = 8 XCD x 64; XCD owns one batch (K/V L2-resident)
  const int bidx = (blockIdx.x & 7) * 64 + (blockIdx.x >> 3);
  const int b  = bidx >> 6;
  const int qw = (bidx & 63) << 6;            // block's 64-q window

  // Q B-frags for BOTH 32-q tiles: col(q)=lane&31, k(c)=16ks+8h+j
  bf16x8 qfA[4], qfB[4];
  {
    const ushort* qa = Qb + ((((size_t)b << 12) + qw + r32) << 6) + h8;
    const ushort* qb2 = Qb + ((((size_t)b << 12) + qw + 32 + r32) << 6) + h8;
    #pragma unroll
    for (int ks = 0; ks < 4; ++ks) {
      qfA[ks] = *(const bf16x8*)(qa + (ks << 4));
      qfB[ks] = *(const bf16x8*)(qb2 + (ks << 4));
    }
  }

  // fragment base pointers for this wave's kv-quarter (kvblk = w*32 + i)
  const ushort* kb = KF + ((size_t)((b << 7) + (w << 5))) * 2048 + (lane << 3);
  const ushort* vb = VF + ((size_t)((b << 7) + (w << 5))) * 2048 + (h << 9) + (r32 << 3);

  const f32x16 Z = (f32x16)(0.0f);
  f32x16 accA0 = Z, accA1 = Z, accB0 = Z, accB1 = Z;
  float lA = 0.f, lB = 0.f;

  // one 32q-tile's S->softmax->EXCH->PV against the already-loaded k/v regs
  #define TILE(QF, A0, A1, LV) do { \
    __builtin_amdgcn_s_setprio(1); \
    f32x16 s = __builtin_amdgcn_mfma_f32_32x32x16_bf16(k0, QF[0], Z, 0, 0, 0); \
    s = __builtin_amdgcn_mfma_f32_32x32x16_bf16(k1, QF[1], s, 0, 0, 0); \
    s = __builtin_amdgcn_mfma_f32_32x32x16_bf16(k2, QF[2], s, 0, 0, 0); \
    s = __builtin_amdgcn_mfma_f32_32x32x16_bf16(k3, QF[3], s, 0, 0, 0); \
    __builtin_amdgcn_s_setprio(0); \
    float rs = 0.f; \
    _Pragma("unroll") \
    for (int ii = 0; ii < 16; ++ii) { \
      float p = __builtin_exp2f(s[ii]); \
      s[ii] = p; \
      rs += p; \
    } \
    LV += rs; \
    bf16x8 pb0, pb1; \
    { \
      uint plo0 = pk2(s[0], s[1]); \
      uint plo1 = pk2(s[2], s[3]); \
      uint phi0 = pk2(s[4], s[5]); \
      uint phi1 = pk2(s[6], s[7]); \
      uint2v r0 = __builtin_amdgcn_permlane32_swap(plo0, phi0, false, false); \
      uint2v r1 = __builtin_amdgcn_permlane32_swap(plo1, phi1, false, false); \
      union { uint u[4]; bf16x8 v; } f_; \
      f_.u[0] = r0.x; f_.u[1] = r1.x; f_.u[2] = r0.y; f_.u[3] = r1.y; \
      pb0 = f_.v; \
    } \
    { \
      uint plo0 = pk2(s[8],  s[9]); \
      uint plo1 = pk2(s[10], s[11]); \
      uint phi0 = pk2(s[12], s[13]); \
      uint phi1 = pk2(s[14], s[15]); \
      uint2v r0 = __builtin_amdgcn_permlane32_swap(plo0, phi0, false, false); \
      uint2v r1 = __builtin_amdgcn_permlane32_swap(plo1, phi1, false, false); \
      union { uint u[4]; bf16x8 v; } f_; \
      f_.u[0] = r0.x; f_.u[1] = r1.x; f_.u[2] = r0.y; f_.u[3] = r1.y; \
      pb1 = f_.v; \
    } \
    __builtin_amdgcn_s_setprio(1); \
    A0 = __builtin_amdgcn_mfma_f32_32x32x16_bf16(v0, pb0, A0, 0, 0, 0); \
    A1 = __builtin_amdgcn_mfma_f32_32x32x16_bf16(v1, pb0, A1, 0, 0, 0); \
    A0 = __builtin_amdgcn_mfma_f32_32x32x16_bf16(v2, pb1, A0, 0, 0, 0); \
    A1 = __builtin_amdgcn_mfma_f32_32x32x16_bf16(v3, pb1, A1, 0, 0, 0); \
    __builtin_amdgcn_s_setprio(0); \
  } while (0)

  #pragma unroll 1
  for (int t = 0; t < 32; ++t) {
    // ---- 8 coalesced fragment loads, shared by BOTH q-tiles ----
    bf16x8 k0 = *(const bf16x8*)(kb);
    bf16x8 k1 = *(const bf16x8*)(kb + 512);
    bf16x8 k2 = *(const bf16x8*)(kb + 1024);
    bf16x8 k3 = *(const bf16x8*)(kb + 1536);
    bf16x8 v0 = *(const bf16x8*)(vb);
    bf16x8 v1 = *(const bf16x8*)(vb + 256);
    bf16x8 v2 = *(const bf16x8*)(vb + 1024);
    bf16x8 v3 = *(const bf16x8*)(vb + 1280);
    kb += 2048; vb += 2048;

    TILE(qfA, accA0, accA1, lA);
    TILE(qfB, accB0, accB1, lB);
  }
  #undef TILE

  // ---- 4-way merge of kv-quarter partials (shared implicit m=0) ----
  float lAm = lA + __shfl_xor(lA, 32);
  float lBm = lB + __shfl_xor(lB, 32);

  if (w != 0) {
    float* p = &cmb[w - 1][lane][0];
    #pragma unroll
    for (int i = 0; i < 16; ++i) {
      p[i]      = accA0[i];
      p[16 + i] = accA1[i];
      p[32 + i] = accB0[i];
      p[48 + i] = accB1[i];
    }
    p[64] = lAm;
    p[65] = lBm;
  }
  __syncthreads();
  if (w == 0) {
    float lsA = lAm, lsB = lBm;
    #pragma unroll
    for (int q = 0; q < 3; ++q) { lsA += cmb[q][lane][64]; lsB += cmb[q][lane][65]; }
    const float invA = 1.0f / lsA;
    const float invB = 1.0f / lsB;
    const size_t rowA = (((size_t)b << 12) + qw + r32) << 6;
    const size_t rowB = (((size_t)b << 12) + qw + 32 + r32) << 6;
    #pragma unroll
    for (int g = 0; g < 4; ++g) {
      f32x4 oA, oB;
      #pragma unroll
      for (int i = 0; i < 4; ++i) {
        float vA0 = accA0[4*g + i], vB0 = accB0[4*g + i];
        #pragma unroll
        for (int q = 0; q < 3; ++q) {
          vA0 += cmb[q][lane][4*g + i];
          vB0 += cmb[q][lane][32 + 4*g + i];
        }
        oA[i] = vA0 * invA;
        oB[i] = vB0 * invB;
      }
      *(f32x4*)(out + rowA + (g << 3) + (h << 2)) = oA;
      *(f32x4*)(out + rowB + (g << 3) + (h << 2)) = oB;
    }
    #pragma unroll
    for (int g = 0; g < 4; ++g) {
      f32x4 oA, oB;
      #pragma unroll
      for (int i = 0; i < 4; ++i) {
        float vA1 = accA1[4*g + i], vB1 = accB1[4*g + i];
        #pragma unroll
        for (int q = 0; q < 3; ++q) {
          vA1 += cmb[q][lane][16 + 4*g + i];
          vB1 += cmb[q][lane][48 + 4*g + i];
        }
        oA[i] = vA1 * invA;
        oB[i] = vB1 * invB;
      }
      *(f32x4*)(out + rowA + 32 + (g << 3) + (h << 2)) = oA;
      *(f32x4*)(out + rowB + 32 + (g << 3) + (h << 2)) = oB;
    }
  }
}

extern "C" void kernel_launch(void* const* d_in, const int* in_sizes, int n_in,
                              void* d_out, int out_size, void* d_ws, size_t ws_size,
                              hipStream_t stream) {
  (void)in_sizes; (void)n_in; (void)out_size; (void)ws_size;
  const float* x  = (const float*)d_in[0];
  const float* Wq = (const float*)d_in[1];
  const float* bq = (const float*)d_in[2];
  const float* Wk = (const float*)d_in[3];
  const float* bk = (const float*)d_in[4];
  const float* Wv = (const float*)d_in[5];
  const float* bv = (const float*)d_in[6];
  float* out = (float*)d_out;

  const size_t SZ = (size_t)B_ * N_ * 64;          // 2,097,152 elems (4 MB)
  ushort* Qb = (ushort*)d_ws;
  ushort* KF = Qb + SZ;
  ushort* VF = KF + SZ;

  proj_kernel<<<dim3(128, 12), dim3(256), 0, stream>>>(x, Wq, bq, Wk, bk, Wv, bv,
                                                       Qb, KF, VF);
  flash_kernel<<<dim3(512), dim3(256), 0, stream>>>(Qb, KF, VF, out);
}

// Round 20
// 71.986 us; speedup vs baseline: 1.1930x; 1.1186x over previous
//
#include <hip/hip_runtime.h>
#include <math.h>

#define B_ 8
#define N_ 4096
// (1/sqrt(7)) * log2(e): Q pre-scale so logits are in base-2 domain (exp2 softmax)
#define SCALE2_ 0.54528747f

typedef __bf16 bf16x8 __attribute__((ext_vector_type(8)));
typedef float f32x4 __attribute__((ext_vector_type(4)));
typedef float f32x16 __attribute__((ext_vector_type(16)));
typedef unsigned short ushortx8 __attribute__((ext_vector_type(8)));
typedef unsigned short ushort;
typedef unsigned int uint;
typedef uint uint2v __attribute__((ext_vector_type(2)));

static __device__ __forceinline__ ushort f2bf(float f) {
  union { float f; unsigned u; } v; v.f = f;
  unsigned r = v.u + 0x7FFFu + ((v.u >> 16) & 1u);  // RNE
  return (ushort)(r >> 16);
}
static __device__ __forceinline__ float bf2f(ushort h) {
  union { unsigned u; float f; } v; v.u = ((unsigned)h) << 16;
  return v.f;
}
static __device__ __forceinline__ uint pk2(float a, float b) {
  union { __bf16 h[2]; uint u; } v;
  v.h[0] = (__bf16)a; v.h[1] = (__bf16)b;
  return v.u;
}

// ---------------------------------------------------------------------------
// Kernel 1: MFMA-based projections (proj was 1024 scalar FMAs/thread = a
// 64x64x32768 GEMM off the matrix cores; ~16us for a ~5us-floor op).
// Grid (256 pixel-blocks, 3 mats), 4 waves x 32 pixels.
// Per wave: x -> bf16 hi/lo B-frags (2-term split, R7-proven lossless here);
// W -> bf16 lane-mapped frags (A-frag for Q/K, B-frag for V -- same lane map,
// HW-proven by flash's fragment reads); 16 MFMAs; bias; pk2+permlane32_swap
// EXCH (flash-PV-proven) -> 16B coalesced stores into the EXACT layouts
// flash consumes:
//   Qb row-major [b][n][64] (Q pre-scaled by SCALE2_)
//   KF[b][kvblk][ks(4)][h(2)][r32(32)][8]
//   VF[b][kvblk][ks2(2)][h(2)][o(64)][8]
// D-layout (m74/m101 + flash-proven): col=lane&31, row=(reg&3)+8(reg>>2)+4h2.
// EXCH group g yields per-lane rows 16g+8h2+j (j=0..7), one 16B chunk.
// ---------------------------------------------------------------------------
__global__ __launch_bounds__(256)
void proj_kernel(const float* __restrict__ x,
                 const float* __restrict__ Wq, const float* __restrict__ bq,
                 const float* __restrict__ Wk, const float* __restrict__ bk,
                 const float* __restrict__ Wv, const float* __restrict__ bv,
                 ushort* __restrict__ Qb, ushort* __restrict__ KF,
                 ushort* __restrict__ VF)
{
  const int tid  = threadIdx.x;
  const int lane = tid & 63;
  const int w    = tid >> 6;       // wave = 32-pixel group
  const int r32  = lane & 31;
  const int h2   = lane >> 5;
  const int mat  = blockIdx.y;     // 0=Q 1=K 2=V

  const int gp0 = blockIdx.x << 7;         // block's 128-pixel base
  const int b   = gp0 >> 12;
  const int nb  = gp0 & 4095;
  const int n   = nb + (w << 5) + r32;     // this lane's pixel

  const float* W    = (mat == 0) ? Wq : (mat == 1) ? Wk : Wv;
  const float* bias = (mat == 0) ? bq : (mat == 1) ? bk : bv;
  const float  scl  = (mat == 0) ? SCALE2_ : 1.0f;

  // ---- x fragments, hi/lo split: lane (pixel=r32, h2) holds c=16ks+8h2+j ----
  bf16x8 xh[4], xl[4];
  #pragma unroll
  for (int ks = 0; ks < 4; ++ks) {
    union { ushort u[8]; bf16x8 v; } th, tl;
    #pragma unroll
    for (int j = 0; j < 8; ++j) {
      const int c = (ks << 4) + (h2 << 3) + j;
      float val = x[((size_t)b << 18) + ((size_t)c << 12) + n];
      ushort hv = f2bf(val);
      th.u[j] = hv;
      tl.u[j] = f2bf(val - bf2f(hv));
    }
    xh[ks] = th.v;
    xl[ks] = tl.v;
  }

  // ---- W fragments: lane o = 32t+r32 holds W[o][c=16ks+8h2+j] (scaled) ----
  bf16x8 wf[2][4];
  #pragma unroll
  for (int t = 0; t < 2; ++t) {
    #pragma unroll
    for (int ks = 0; ks < 4; ++ks) {
      const float* wp = W + (((t << 5) + r32) << 6) + (ks << 4) + (h2 << 3);
      float4 a  = *(const float4*)wp;
      float4 c4 = *(const float4*)(wp + 4);
      union { ushort u[8]; bf16x8 v; } tw;
      tw.u[0] = f2bf(a.x * scl);  tw.u[1] = f2bf(a.y * scl);
      tw.u[2] = f2bf(a.z * scl);  tw.u[3] = f2bf(a.w * scl);
      tw.u[4] = f2bf(c4.x * scl); tw.u[5] = f2bf(c4.y * scl);
      tw.u[6] = f2bf(c4.z * scl); tw.u[7] = f2bf(c4.w * scl);
      wf[t][ks] = tw.v;
    }
  }

  const f32x16 Z = (f32x16)(0.0f);
  const size_t rowb = (((size_t)b << 12) + n) << 6;                 // Qb row
  const size_t kfb  = ((size_t)(b * 128 + (nb >> 5) + w)) * 2048;   // K/V blk

  #pragma unroll
  for (int t = 0; t < 2; ++t) {
    // ---- GEMM: Q/K: D[o][pixel] = W x; V: D[pixel][o] = x^T W^T ----
    f32x16 Dh = Z, Dl = Z;
    if (mat == 2) {
      #pragma unroll
      for (int ks = 0; ks < 4; ++ks) {
        Dh = __builtin_amdgcn_mfma_f32_32x32x16_bf16(xh[ks], wf[t][ks], Dh, 0, 0, 0);
        Dl = __builtin_amdgcn_mfma_f32_32x32x16_bf16(xl[ks], wf[t][ks], Dl, 0, 0, 0);
      }
    } else {
      #pragma unroll
      for (int ks = 0; ks < 4; ++ks) {
        Dh = __builtin_amdgcn_mfma_f32_32x32x16_bf16(wf[t][ks], xh[ks], Dh, 0, 0, 0);
        Dl = __builtin_amdgcn_mfma_f32_32x32x16_bf16(wf[t][ks], xl[ks], Dl, 0, 0, 0);
      }
    }

    // ---- bias (V: uniform per lane-col; Q/K: D-row-mapped) ----
    f32x16 D;
    if (mat == 2) {
      const float bvl = bias[(t << 5) + r32];
      #pragma unroll
      for (int i = 0; i < 16; ++i) D[i] = Dh[i] + Dl[i] + bvl;
    } else {
      float bm[16];
      #pragma unroll
      for (int g2 = 0; g2 < 4; ++g2) {
        float4 t4 = *(const float4*)(bias + (t << 5) + (g2 << 3) + (h2 << 2));
        bm[4*g2+0] = t4.x * scl; bm[4*g2+1] = t4.y * scl;
        bm[4*g2+2] = t4.z * scl; bm[4*g2+3] = t4.w * scl;
      }
      #pragma unroll
      for (int i = 0; i < 16; ++i) D[i] = Dh[i] + Dl[i] + bm[i];
    }

    // ---- EXCH -> per-lane 16B chunk of rows 16g+8h2+j, then store ----
    #pragma unroll
    for (int g = 0; g < 2; ++g) {
      uint plo0 = pk2(D[8*g+0], D[8*g+1]);
      uint plo1 = pk2(D[8*g+2], D[8*g+3]);
      uint phi0 = pk2(D[8*g+4], D[8*g+5]);
      uint phi1 = pk2(D[8*g+6], D[8*g+7]);
      uint2v r0 = __builtin_amdgcn_permlane32_swap(plo0, phi0, false, false);
      uint2v r1 = __builtin_amdgcn_permlane32_swap(plo1, phi1, false, false);
      union { uint u[4]; ushortx8 v8; } ch;
      ch.u[0] = r0.x; ch.u[1] = r1.x; ch.u[2] = r0.y; ch.u[3] = r1.y;
      if (mat == 0) {
        // rows = o-chunk: o0 = 32t + 16g + 8h2
        *(ushortx8*)(Qb + rowb + (t << 5) + (g << 4) + (h2 << 3)) = ch.v8;
      } else if (mat == 1) {
        // rows = o-chunk: ks = 2t+g, h = h2, r32 = pixel
        *(ushortx8*)(KF + kfb + ((2*t + g) << 9) + (h2 << 8) + (r32 << 3)) = ch.v8;
      } else {
        // rows = pixel-chunk: ks2 = g, h = h2, o = 32t + r32
        *(ushortx8*)(VF + kfb + (g << 10) + (h2 << 9) + (((t << 5) + r32) << 3)) = ch.v8;
      }
    }
  }
}

// ---------------------------------------------------------------------------
// Kernel 2: flash attention (R16/R19 measured-best, byte-identical).
// Fragment-direct from L2 + 64q-per-wave K/V reuse. 512 blocks = (b, 64q) x
// 4 waves (kv-quarters); zero main-loop barriers; max-free exp2 softmax,
// permlane32_swap EXCH, 4-way LDS merge epilogue.
// ---------------------------------------------------------------------------
__global__ __launch_bounds__(256, 2)
void flash_kernel(const ushort* __restrict__ Qb, const ushort* __restrict__ KF,
                  const ushort* __restrict__ VF, float* __restrict__ out)
{
  __shared__ float cmb[3][64][66];   // 50688 B, end merge only

  const int tid  = threadIdx.x;
  const int lane = tid & 63;
  const int w    = tid >> 6;       // kv-quarter 0..3
  const int r32  = lane & 31;
  const int h    = lane >> 5;      // 0..1
  const int h8   = h << 3;

  // 512 blocks = 8 XCD x 64; XCD owns one batch (K/V L2-resident)
  const int bidx = (blockIdx.x & 7) * 64 + (blockIdx.x >> 3);
  const int b  = bidx >> 6;
  const int qw = (bidx & 63) << 6;            // block's 64-q window

  // Q B-frags for BOTH 32-q tiles: col(q)=lane&31, k(c)=16ks+8h+j
  bf16x8 qfA[4], qfB[4];
  {
    const ushort* qa = Qb + ((((size_t)b << 12) + qw + r32) << 6) + h8;
    const ushort* qb2 = Qb + ((((size_t)b << 12) + qw + 32 + r32) << 6) + h8;
    #pragma unroll
    for (int ks = 0; ks < 4; ++ks) {
      qfA[ks] = *(const bf16x8*)(qa + (ks << 4));
      qfB[ks] = *(const bf16x8*)(qb2 + (ks << 4));
    }
  }

  // fragment base pointers for this wave's kv-quarter (kvblk = w*32 + i)
  const ushort* kb = KF + ((size_t)((b << 7) + (w << 5))) * 2048 + (lane << 3);
  const ushort* vb = VF + ((size_t)((b << 7) + (w << 5))) * 2048 + (h << 9) + (r32 << 3);

  const f32x16 Z = (f32x16)(0.0f);
  f32x16 accA0 = Z, accA1 = Z, accB0 = Z, accB1 = Z;
  float lA = 0.f, lB = 0.f;

  // one 32q-tile's S->softmax->EXCH->PV against the already-loaded k/v regs
  #define TILE(QF, A0, A1, LV) do { \
    __builtin_amdgcn_s_setprio(1); \
    f32x16 s = __builtin_amdgcn_mfma_f32_32x32x16_bf16(k0, QF[0], Z, 0, 0, 0); \
    s = __builtin_amdgcn_mfma_f32_32x32x16_bf16(k1, QF[1], s, 0, 0, 0); \
    s = __builtin_amdgcn_mfma_f32_32x32x16_bf16(k2, QF[2], s, 0, 0, 0); \
    s = __builtin_amdgcn_mfma_f32_32x32x16_bf16(k3, QF[3], s, 0, 0, 0); \
    __builtin_amdgcn_s_setprio(0); \
    float rs = 0.f; \
    _Pragma("unroll") \
    for (int ii = 0; ii < 16; ++ii) { \
      float p = __builtin_exp2f(s[ii]); \
      s[ii] = p; \
      rs += p; \
    } \
    LV += rs; \
    bf16x8 pb0, pb1; \
    { \
      uint plo0 = pk2(s[0], s[1]); \
      uint plo1 = pk2(s[2], s[3]); \
      uint phi0 = pk2(s[4], s[5]); \
      uint phi1 = pk2(s[6], s[7]); \
      uint2v r0 = __builtin_amdgcn_permlane32_swap(plo0, phi0, false, false); \
      uint2v r1 = __builtin_amdgcn_permlane32_swap(plo1, phi1, false, false); \
      union { uint u[4]; bf16x8 v; } f_; \
      f_.u[0] = r0.x; f_.u[1] = r1.x; f_.u[2] = r0.y; f_.u[3] = r1.y; \
      pb0 = f_.v; \
    } \
    { \
      uint plo0 = pk2(s[8],  s[9]); \
      uint plo1 = pk2(s[10], s[11]); \
      uint phi0 = pk2(s[12], s[13]); \
      uint phi1 = pk2(s[14], s[15]); \
      uint2v r0 = __builtin_amdgcn_permlane32_swap(plo0, phi0, false, false); \
      uint2v r1 = __builtin_amdgcn_permlane32_swap(plo1, phi1, false, false); \
      union { uint u[4]; bf16x8 v; } f_; \
      f_.u[0] = r0.x; f_.u[1] = r1.x; f_.u[2] = r0.y; f_.u[3] = r1.y; \
      pb1 = f_.v; \
    } \
    __builtin_amdgcn_s_setprio(1); \
    A0 = __builtin_amdgcn_mfma_f32_32x32x16_bf16(v0, pb0, A0, 0, 0, 0); \
    A1 = __builtin_amdgcn_mfma_f32_32x32x16_bf16(v1, pb0, A1, 0, 0, 0); \
    A0 = __builtin_amdgcn_mfma_f32_32x32x16_bf16(v2, pb1, A0, 0, 0, 0); \
    A1 = __builtin_amdgcn_mfma_f32_32x32x16_bf16(v3, pb1, A1, 0, 0, 0); \
    __builtin_amdgcn_s_setprio(0); \
  } while (0)

  #pragma unroll 1
  for (int t = 0; t < 32; ++t) {
    // ---- 8 coalesced fragment loads, shared by BOTH q-tiles ----
    bf16x8 k0 = *(const bf16x8*)(kb);
    bf16x8 k1 = *(const bf16x8*)(kb + 512);
    bf16x8 k2 = *(const bf16x8*)(kb + 1024);
    bf16x8 k3 = *(const bf16x8*)(kb + 1536);
    bf16x8 v0 = *(const bf16x8*)(vb);
    bf16x8 v1 = *(const bf16x8*)(vb + 256);
    bf16x8 v2 = *(const bf16x8*)(vb + 1024);
    bf16x8 v3 = *(const bf16x8*)(vb + 1280);
    kb += 2048; vb += 2048;

    TILE(qfA, accA0, accA1, lA);
    TILE(qfB, accB0, accB1, lB);
  }
  #undef TILE

  // ---- 4-way merge of kv-quarter partials (shared implicit m=0) ----
  float lAm = lA + __shfl_xor(lA, 32);
  float lBm = lB + __shfl_xor(lB, 32);

  if (w != 0) {
    float* p = &cmb[w - 1][lane][0];
    #pragma unroll
    for (int i = 0; i < 16; ++i) {
      p[i]      = accA0[i];
      p[16 + i] = accA1[i];
      p[32 + i] = accB0[i];
      p[48 + i] = accB1[i];
    }
    p[64] = lAm;
    p[65] = lBm;
  }
  __syncthreads();
  if (w == 0) {
    float lsA = lAm, lsB = lBm;
    #pragma unroll
    for (int q = 0; q < 3; ++q) { lsA += cmb[q][lane][64]; lsB += cmb[q][lane][65]; }
    const float invA = 1.0f / lsA;
    const float invB = 1.0f / lsB;
    const size_t rowA = (((size_t)b << 12) + qw + r32) << 6;
    const size_t rowB = (((size_t)b << 12) + qw + 32 + r32) << 6;
    #pragma unroll
    for (int g = 0; g < 4; ++g) {
      f32x4 oA, oB;
      #pragma unroll
      for (int i = 0; i < 4; ++i) {
        float vA0 = accA0[4*g + i], vB0 = accB0[4*g + i];
        #pragma unroll
        for (int q = 0; q < 3; ++q) {
          vA0 += cmb[q][lane][4*g + i];
          vB0 += cmb[q][lane][32 + 4*g + i];
        }
        oA[i] = vA0 * invA;
        oB[i] = vB0 * invB;
      }
      *(f32x4*)(out + rowA + (g << 3) + (h << 2)) = oA;
      *(f32x4*)(out + rowB + (g << 3) + (h << 2)) = oB;
    }
    #pragma unroll
    for (int g = 0; g < 4; ++g) {
      f32x4 oA, oB;
      #pragma unroll
      for (int i = 0; i < 4; ++i) {
        float vA1 = accA1[4*g + i], vB1 = accB1[4*g + i];
        #pragma unroll
        for (int q = 0; q < 3; ++q) {
          vA1 += cmb[q][lane][16 + 4*g + i];
          vB1 += cmb[q][lane][48 + 4*g + i];
        }
        oA[i] = vA1 * invA;
        oB[i] = vB1 * invB;
      }
      *(f32x4*)(out + rowA + 32 + (g << 3) + (h << 2)) = oA;
      *(f32x4*)(out + rowB + 32 + (g << 3) + (h << 2)) = oB;
    }
  }
}

extern "C" void kernel_launch(void* const* d_in, const int* in_sizes, int n_in,
                              void* d_out, int out_size, void* d_ws, size_t ws_size,
                              hipStream_t stream) {
  (void)in_sizes; (void)n_in; (void)out_size; (void)ws_size;
  const float* x  = (const float*)d_in[0];
  const float* Wq = (const float*)d_in[1];
  const float* bq = (const float*)d_in[2];
  const float* Wk = (const float*)d_in[3];
  const float* bk = (const float*)d_in[4];
  const float* Wv = (const float*)d_in[5];
  const float* bv = (const float*)d_in[6];
  float* out = (float*)d_out;

  const size_t SZ = (size_t)B_ * N_ * 64;          // 2,097,152 elems (4 MB)
  ushort* Qb = (ushort*)d_ws;
  ushort* KF = Qb + SZ;
  ushort* VF = KF + SZ;

  proj_kernel<<<dim3(256, 3), dim3(256), 0, stream>>>(x, Wq, bq, Wk, bk, Wv, bv,
                                                      Qb, KF, VF);
  flash_kernel<<<dim3(512), dim3(256), 0, stream>>>(Qb, KF, VF, out);
}